// Round 1
// baseline (285.492 us; speedup 1.0000x reference)
//
#include <hip/hip_runtime.h>
#include <math.h>

#define BB 2
#define NN 4096
#define CC 33
#define CP 36                         // padded row pitch (floats), 144B = 16B-aligned rows
#define TILE 64
#define NTILES (NN / TILE)            // 64
#define NTRI ((NTILES * (NTILES + 1)) / 2)  // 2080 upper-triangle tiles per batch

// ---------------- kernel 1: per-row softmax + CE/focal/dice accumulators ----
__global__ __launch_bounds__(256) void row_kernel(
    const float* __restrict__ pred, const int* __restrict__ targets,
    const int* __restrict__ pred_choice, float* __restrict__ p,
    float* __restrict__ sqn, double* __restrict__ acc, int* __restrict__ matches)
{
    int lane = threadIdx.x & 63;
    int wave = threadIdx.x >> 6;
    int row = blockIdx.x * 4 + wave;
    if (row >= BB * NN) return;

    float v = (lane < CC) ? pred[(size_t)row * CC + lane] : -INFINITY;

    float m = v;
    #pragma unroll
    for (int off = 32; off; off >>= 1) m = fmaxf(m, __shfl_xor(m, off));

    float e = (lane < CC) ? expf(v - m) : 0.0f;
    float s = e;
    #pragma unroll
    for (int off = 32; off; off >>= 1) s += __shfl_xor(s, off);

    float pv = e / s;                        // 0 for lanes >= 33 (incl. pad cols)
    if (lane < CP) p[(size_t)row * CP + lane] = pv;

    float sq = pv * pv;
    #pragma unroll
    for (int off = 32; off; off >>= 1) sq += __shfl_xor(sq, off);

    int t = targets[row];
    float vt = __shfl(v, t);
    float pt = __shfl(pv, t);
    float logpt = (vt - m) - logf(s);

    if (lane == 0) {
        sqn[row] = sq;
        atomicAdd(&acc[0], (double)(-logpt));           // ce sum
        float om = 1.0f - pt;
        atomicAdd(&acc[1], (double)(om * om));          // focal sum
        if (t == pred_choice[row]) atomicAdd(matches, 1);
    }
}

// ---------------- kernel 2: upper-triangle pairwise-distance sum ------------
__global__ __launch_bounds__(256) void pair_kernel(
    const float* __restrict__ p, const float* __restrict__ sqn,
    double* __restrict__ acc)
{
    __shared__ __align__(16) float spi[TILE][CP];
    __shared__ __align__(16) float spj[TILE][CP];
    __shared__ float ssqi[TILE];
    __shared__ float ssqj[TILE];
    __shared__ float red[4];

    int bid = blockIdx.x;
    int b = bid / NTRI;
    int t = bid % NTRI;

    // decode (ti, tj), ti <= tj, row-major upper triangle
    float disc = (NTILES + 0.5f) * (NTILES + 0.5f) - 2.0f * (float)t;
    int ti = (int)(NTILES + 0.5f - sqrtf(disc));
    if (ti < 0) ti = 0;
    if (ti > NTILES - 1) ti = NTILES - 1;
    while (ti > 0 && (ti * NTILES - ti * (ti - 1) / 2) > t) --ti;
    while (((ti + 1) * NTILES - (ti + 1) * ti / 2) <= t) ++ti;
    int tj = ti + (t - (ti * NTILES - ti * (ti - 1) / 2));

    int i0 = ti * TILE, j0 = tj * TILE;

    const float4* pb4 = (const float4*)(p + (size_t)b * NN * CP);
    float4* spi4 = (float4*)&spi[0][0];
    float4* spj4 = (float4*)&spj[0][0];
    #pragma unroll
    for (int idx = threadIdx.x; idx < TILE * (CP / 4); idx += 256) {
        int r = idx / (CP / 4), q = idx % (CP / 4);
        spi4[idx] = pb4[(size_t)(i0 + r) * (CP / 4) + q];
        spj4[idx] = pb4[(size_t)(j0 + r) * (CP / 4) + q];
    }
    if (threadIdx.x < TILE)
        ssqi[threadIdx.x] = sqn[b * NN + i0 + threadIdx.x];
    else if (threadIdx.x < 2 * TILE)
        ssqj[threadIdx.x - TILE] = sqn[b * NN + j0 + (threadIdx.x - TILE)];
    __syncthreads();

    int tx = threadIdx.x & 15, ty = threadIdx.x >> 4;

    float accd[4][4];
    #pragma unroll
    for (int r = 0; r < 4; r++)
        #pragma unroll
        for (int s = 0; s < 4; s++) accd[r][s] = 0.0f;

    #pragma unroll
    for (int q = 0; q < 8; q++) {          // c = 0..31 in float4 quads
        float4 a[4], bv[4];
        #pragma unroll
        for (int r = 0; r < 4; r++) a[r] = *(const float4*)&spi[ty * 4 + r][q * 4];
        #pragma unroll
        for (int s = 0; s < 4; s++) bv[s] = *(const float4*)&spj[tx * 4 + s][q * 4];
        #pragma unroll
        for (int r = 0; r < 4; r++)
            #pragma unroll
            for (int s = 0; s < 4; s++) {
                accd[r][s] = fmaf(a[r].x, bv[s].x, accd[r][s]);
                accd[r][s] = fmaf(a[r].y, bv[s].y, accd[r][s]);
                accd[r][s] = fmaf(a[r].z, bv[s].z, accd[r][s]);
                accd[r][s] = fmaf(a[r].w, bv[s].w, accd[r][s]);
            }
    }
    {   // remainder c = 32
        float a[4], bv[4];
        #pragma unroll
        for (int r = 0; r < 4; r++) a[r] = spi[ty * 4 + r][32];
        #pragma unroll
        for (int s = 0; s < 4; s++) bv[s] = spj[tx * 4 + s][32];
        #pragma unroll
        for (int r = 0; r < 4; r++)
            #pragma unroll
            for (int s = 0; s < 4; s++) accd[r][s] = fmaf(a[r], bv[s], accd[r][s]);
    }

    float ssum = 0.0f;
    #pragma unroll
    for (int r = 0; r < 4; r++) {
        int gi = i0 + ty * 4 + r;
        float sqi = ssqi[ty * 4 + r];
        #pragma unroll
        for (int s = 0; s < 4; s++) {
            int gj = j0 + tx * 4 + s;
            float d2 = sqi + ssqj[tx * 4 + s] - 2.0f * accd[r][s];
            float d = (d2 > 0.0f) ? sqrtf(d2) : 0.0f;
            ssum += (gj > gi) ? d : 0.0f;   // strict upper triangle only
        }
    }

    #pragma unroll
    for (int off = 32; off; off >>= 1) ssum += __shfl_xor(ssum, off);
    if ((threadIdx.x & 63) == 0) red[threadIdx.x >> 6] = ssum;
    __syncthreads();
    if (threadIdx.x == 0)
        atomicAdd(&acc[2], (double)(red[0] + red[1] + red[2] + red[3]));
}

// ---------------- kernel 3: finalize ----------------------------------------
__global__ void final_kernel(const double* __restrict__ acc,
                             const int* __restrict__ matches,
                             float* __restrict__ out)
{
    double BN = (double)(BB * NN);
    double ce = acc[0] / BN;
    double fo = acc[1] / BN;
    double loss = ce * fo;
    double dice = 1.0 - 2.0 * ((double)(*matches) + 1.0) / (2.0 * BN + 1.0);
    double S = 2.0 * acc[2];                 // full matrix sum (diag = 0)
    double mean_pred = S / (BN * (double)NN);
    double dml = 0.05 * log(0.05) - 0.05 * mean_pred;
    out[0] = (float)(loss + dice + dml);
}

extern "C" void kernel_launch(void* const* d_in, const int* in_sizes, int n_in,
                              void* d_out, int out_size, void* d_ws, size_t ws_size,
                              hipStream_t stream)
{
    const float* pred        = (const float*)d_in[0];
    // d_in[1] = y_ohe: unused — the double-where provably collapses dis_map to 0.05
    const int*   targets     = (const int*)d_in[2];
    const int*   pred_choice = (const int*)d_in[3];

    char* ws = (char*)d_ws;
    float* p = (float*)ws;                                   // BB*NN*CP floats
    size_t off = (size_t)BB * NN * CP * sizeof(float);
    float* sqn = (float*)(ws + off);
    off += (size_t)BB * NN * sizeof(float);
    off = (off + 7) & ~(size_t)7;
    double* acc = (double*)(ws + off);                       // [ce, focal, tri_sum]
    int* matches = (int*)(ws + off + 3 * sizeof(double));

    hipMemsetAsync(ws + off, 0, 3 * sizeof(double) + sizeof(int), stream);

    row_kernel<<<(BB * NN) / 4, 256, 0, stream>>>(pred, targets, pred_choice,
                                                  p, sqn, acc, matches);
    pair_kernel<<<BB * NTRI, 256, 0, stream>>>(p, sqn, acc);
    final_kernel<<<1, 1, 0, stream>>>(acc, matches, (float*)d_out);
}

// Round 2
// 67.025 us; speedup vs baseline: 4.2595x; 4.2595x over previous
//
#include <hip/hip_runtime.h>
#include <math.h>

#define BB 2
#define NN 4096
#define CC 33
#define CP 36                         // padded row pitch (floats), 144B = 16B-aligned rows
#define TILE 64
#define NTILES (NN / TILE)            // 64
#define NTRI ((NTILES * (NTILES + 1)) / 2)  // 2080 upper-triangle tiles per batch
#define ROWBLK ((BB * NN) / 4)        // 2048 row-kernel blocks (4 waves = 4 rows each)
#define PAIRBLK (BB * NTRI)           // 4160 pair-kernel blocks

// ---------------- kernel 1: per-row softmax + per-block CE/focal/match partials
__global__ __launch_bounds__(256) void row_kernel(
    const float* __restrict__ pred, const int* __restrict__ targets,
    const int* __restrict__ pred_choice, float* __restrict__ p,
    float* __restrict__ sqn, float2* __restrict__ part_row,
    int* __restrict__ part_match)
{
    __shared__ float2 lds_cf[4];
    __shared__ int lds_mt[4];

    int lane = threadIdx.x & 63;
    int wave = threadIdx.x >> 6;
    int row = blockIdx.x * 4 + wave;

    float v = (lane < CC) ? pred[(size_t)row * CC + lane] : -INFINITY;

    float m = v;
    #pragma unroll
    for (int off = 32; off; off >>= 1) m = fmaxf(m, __shfl_xor(m, off));

    float e = (lane < CC) ? expf(v - m) : 0.0f;
    float s = e;
    #pragma unroll
    for (int off = 32; off; off >>= 1) s += __shfl_xor(s, off);

    float pv = e / s;                        // 0 for lanes >= 33 (incl. pad cols)
    if (lane < CP) p[(size_t)row * CP + lane] = pv;

    float sq = pv * pv;
    #pragma unroll
    for (int off = 32; off; off >>= 1) sq += __shfl_xor(sq, off);

    int t = targets[row];
    float vt = __shfl(v, t);
    float pt = __shfl(pv, t);
    float logpt = (vt - m) - logf(s);

    if (lane == 0) {
        sqn[row] = sq;
        float om = 1.0f - pt;
        lds_cf[wave] = make_float2(-logpt, om * om);
        lds_mt[wave] = (t == pred_choice[row]) ? 1 : 0;
    }
    __syncthreads();
    if (threadIdx.x == 0) {
        float2 a = lds_cf[0], b = lds_cf[1], c = lds_cf[2], d = lds_cf[3];
        part_row[blockIdx.x] = make_float2(a.x + b.x + c.x + d.x,
                                           a.y + b.y + c.y + d.y);
        part_match[blockIdx.x] = lds_mt[0] + lds_mt[1] + lds_mt[2] + lds_mt[3];
    }
}

// ---------------- kernel 2: upper-triangle pairwise-distance partial sums ----
__global__ __launch_bounds__(256) void pair_kernel(
    const float* __restrict__ p, const float* __restrict__ sqn,
    float* __restrict__ part_pair)
{
    __shared__ __align__(16) float spi[TILE][CP];
    __shared__ __align__(16) float spj[TILE][CP];
    __shared__ float ssqi[TILE];
    __shared__ float ssqj[TILE];
    __shared__ float red[4];

    int bid = blockIdx.x;
    int b = bid / NTRI;
    int t = bid % NTRI;

    // decode (ti, tj), ti <= tj, row-major upper triangle
    float disc = (NTILES + 0.5f) * (NTILES + 0.5f) - 2.0f * (float)t;
    int ti = (int)(NTILES + 0.5f - sqrtf(disc));
    if (ti < 0) ti = 0;
    if (ti > NTILES - 1) ti = NTILES - 1;
    while (ti > 0 && (ti * NTILES - ti * (ti - 1) / 2) > t) --ti;
    while (((ti + 1) * NTILES - (ti + 1) * ti / 2) <= t) ++ti;
    int tj = ti + (t - (ti * NTILES - ti * (ti - 1) / 2));

    int i0 = ti * TILE, j0 = tj * TILE;

    const float4* pb4 = (const float4*)(p + (size_t)b * NN * CP);
    float4* spi4 = (float4*)&spi[0][0];
    float4* spj4 = (float4*)&spj[0][0];
    #pragma unroll
    for (int idx = threadIdx.x; idx < TILE * (CP / 4); idx += 256) {
        int r = idx / (CP / 4), q = idx % (CP / 4);
        spi4[idx] = pb4[(size_t)(i0 + r) * (CP / 4) + q];
        spj4[idx] = pb4[(size_t)(j0 + r) * (CP / 4) + q];
    }
    if (threadIdx.x < TILE)
        ssqi[threadIdx.x] = sqn[b * NN + i0 + threadIdx.x];
    else if (threadIdx.x < 2 * TILE)
        ssqj[threadIdx.x - TILE] = sqn[b * NN + j0 + (threadIdx.x - TILE)];
    __syncthreads();

    int tx = threadIdx.x & 15, ty = threadIdx.x >> 4;

    float accd[4][4];
    #pragma unroll
    for (int r = 0; r < 4; r++)
        #pragma unroll
        for (int s = 0; s < 4; s++) accd[r][s] = 0.0f;

    #pragma unroll
    for (int q = 0; q < 8; q++) {          // c = 0..31 in float4 quads
        float4 a[4], bv[4];
        #pragma unroll
        for (int r = 0; r < 4; r++) a[r] = *(const float4*)&spi[ty * 4 + r][q * 4];
        #pragma unroll
        for (int s = 0; s < 4; s++) bv[s] = *(const float4*)&spj[tx * 4 + s][q * 4];
        #pragma unroll
        for (int r = 0; r < 4; r++)
            #pragma unroll
            for (int s = 0; s < 4; s++) {
                accd[r][s] = fmaf(a[r].x, bv[s].x, accd[r][s]);
                accd[r][s] = fmaf(a[r].y, bv[s].y, accd[r][s]);
                accd[r][s] = fmaf(a[r].z, bv[s].z, accd[r][s]);
                accd[r][s] = fmaf(a[r].w, bv[s].w, accd[r][s]);
            }
    }
    {   // remainder c = 32
        float a[4], bv[4];
        #pragma unroll
        for (int r = 0; r < 4; r++) a[r] = spi[ty * 4 + r][32];
        #pragma unroll
        for (int s = 0; s < 4; s++) bv[s] = spj[tx * 4 + s][32];
        #pragma unroll
        for (int r = 0; r < 4; r++)
            #pragma unroll
            for (int s = 0; s < 4; s++) accd[r][s] = fmaf(a[r], bv[s], accd[r][s]);
    }

    float ssum = 0.0f;
    #pragma unroll
    for (int r = 0; r < 4; r++) {
        int gi = i0 + ty * 4 + r;
        float sqi = ssqi[ty * 4 + r];
        #pragma unroll
        for (int s = 0; s < 4; s++) {
            int gj = j0 + tx * 4 + s;
            float d2 = sqi + ssqj[tx * 4 + s] - 2.0f * accd[r][s];
            float d = (d2 > 0.0f) ? sqrtf(d2) : 0.0f;
            ssum += (gj > gi) ? d : 0.0f;   // strict upper triangle only
        }
    }

    #pragma unroll
    for (int off = 32; off; off >>= 1) ssum += __shfl_xor(ssum, off);
    if ((threadIdx.x & 63) == 0) red[threadIdx.x >> 6] = ssum;
    __syncthreads();
    if (threadIdx.x == 0)
        part_pair[bid] = red[0] + red[1] + red[2] + red[3];
}

// ---------------- kernel 3: reduce partials + finalize -----------------------
__global__ __launch_bounds__(256) void final_kernel(
    const float2* __restrict__ part_row, const int* __restrict__ part_match,
    const float* __restrict__ part_pair, float* __restrict__ out)
{
    __shared__ double lds_ce[4], lds_fo[4], lds_pr[4];
    __shared__ int lds_mt[4];

    double ce = 0.0, fo = 0.0, pr = 0.0;
    int mt = 0;
    for (int i = threadIdx.x; i < ROWBLK; i += 256) {
        float2 v = part_row[i];
        ce += (double)v.x;
        fo += (double)v.y;
        mt += part_match[i];
    }
    for (int i = threadIdx.x; i < PAIRBLK; i += 256)
        pr += (double)part_pair[i];

    #pragma unroll
    for (int off = 32; off; off >>= 1) {
        ce += __shfl_xor(ce, off);
        fo += __shfl_xor(fo, off);
        pr += __shfl_xor(pr, off);
        mt += __shfl_xor(mt, off);
    }
    int wave = threadIdx.x >> 6;
    if ((threadIdx.x & 63) == 0) {
        lds_ce[wave] = ce; lds_fo[wave] = fo; lds_pr[wave] = pr; lds_mt[wave] = mt;
    }
    __syncthreads();
    if (threadIdx.x == 0) {
        double tce = lds_ce[0] + lds_ce[1] + lds_ce[2] + lds_ce[3];
        double tfo = lds_fo[0] + lds_fo[1] + lds_fo[2] + lds_fo[3];
        double tpr = lds_pr[0] + lds_pr[1] + lds_pr[2] + lds_pr[3];
        int    tmt = lds_mt[0] + lds_mt[1] + lds_mt[2] + lds_mt[3];

        double BN = (double)(BB * NN);
        double loss = (tce / BN) * (tfo / BN);
        double dice = 1.0 - 2.0 * ((double)tmt + 1.0) / (2.0 * BN + 1.0);
        double S = 2.0 * tpr;                    // full matrix sum (diag = 0)
        double mean_pred = S / (BN * (double)NN);
        double dml = 0.05 * log(0.05) - 0.05 * mean_pred;
        out[0] = (float)(loss + dice + dml);
    }
}

extern "C" void kernel_launch(void* const* d_in, const int* in_sizes, int n_in,
                              void* d_out, int out_size, void* d_ws, size_t ws_size,
                              hipStream_t stream)
{
    const float* pred        = (const float*)d_in[0];
    // d_in[1] = y_ohe: unused — the double-where provably collapses dis_map to 0.05
    const int*   targets     = (const int*)d_in[2];
    const int*   pred_choice = (const int*)d_in[3];

    char* ws = (char*)d_ws;
    size_t off = 0;
    float* p = (float*)ws;                                   // BB*NN*CP floats
    off += (size_t)BB * NN * CP * sizeof(float);
    float* sqn = (float*)(ws + off);
    off += (size_t)BB * NN * sizeof(float);
    off = (off + 15) & ~(size_t)15;
    float2* part_row = (float2*)(ws + off);                  // ROWBLK float2
    off += (size_t)ROWBLK * sizeof(float2);
    int* part_match = (int*)(ws + off);                      // ROWBLK int
    off += (size_t)ROWBLK * sizeof(int);
    float* part_pair = (float*)(ws + off);                   // PAIRBLK float
    off += (size_t)PAIRBLK * sizeof(float);

    row_kernel<<<ROWBLK, 256, 0, stream>>>(pred, targets, pred_choice,
                                           p, sqn, part_row, part_match);
    pair_kernel<<<PAIRBLK, 256, 0, stream>>>(p, sqn, part_pair);
    final_kernel<<<1, 256, 0, stream>>>(part_row, part_match, part_pair,
                                        (float*)d_out);
}

// Round 3
// 46.983 us; speedup vs baseline: 6.0764x; 1.4266x over previous
//
#include <hip/hip_runtime.h>
#include <math.h>

#define BB 2
#define NN 4096
#define CC 33
#define CP 36                         // padded row pitch in workspace (floats) = 9 float4
#define TILE 64
#define NTILES (NN / TILE)            // 64
#define NTRI ((NTILES * (NTILES + 1)) / 2)  // 2080 upper-triangle tiles per batch
#define ROWBLK ((BB * NN) / 4)        // 2048 row-kernel blocks (4 waves = 4 rows each)
#define PAIRBLK (BB * NTRI)           // 4160 pair-kernel blocks

// ---------------- kernel 1: per-row softmax + per-block CE/focal/match partials
__global__ __launch_bounds__(256) void row_kernel(
    const float* __restrict__ pred, const int* __restrict__ targets,
    const int* __restrict__ pred_choice, float* __restrict__ p,
    float* __restrict__ sqn, float2* __restrict__ part_row,
    int* __restrict__ part_match)
{
    __shared__ float2 lds_cf[4];
    __shared__ int lds_mt[4];

    int lane = threadIdx.x & 63;
    int wave = threadIdx.x >> 6;
    int row = blockIdx.x * 4 + wave;

    float v = (lane < CC) ? pred[(size_t)row * CC + lane] : -INFINITY;

    float m = v;
    #pragma unroll
    for (int off = 32; off; off >>= 1) m = fmaxf(m, __shfl_xor(m, off));

    float e = (lane < CC) ? expf(v - m) : 0.0f;
    float s = e;
    #pragma unroll
    for (int off = 32; off; off >>= 1) s += __shfl_xor(s, off);

    float pv = e / s;                        // 0 for lanes >= 33 (incl. pad cols)
    if (lane < CP) p[(size_t)row * CP + lane] = pv;

    float sq = pv * pv;
    #pragma unroll
    for (int off = 32; off; off >>= 1) sq += __shfl_xor(sq, off);

    int t = targets[row];
    float vt = __shfl(v, t);
    float pt = __shfl(pv, t);
    float logpt = (vt - m) - logf(s);

    if (lane == 0) {
        sqn[row] = sq;
        float om = 1.0f - pt;
        lds_cf[wave] = make_float2(-logpt, om * om);
        lds_mt[wave] = (t == pred_choice[row]) ? 1 : 0;
    }
    __syncthreads();
    if (threadIdx.x == 0) {
        float2 a = lds_cf[0], b = lds_cf[1], c = lds_cf[2], d = lds_cf[3];
        part_row[blockIdx.x] = make_float2(a.x + b.x + c.x + d.x,
                                           a.y + b.y + c.y + d.y);
        part_match[blockIdx.x] = lds_mt[0] + lds_mt[1] + lds_mt[2] + lds_mt[3];
    }
}

// ---------------- kernel 2: upper-triangle pairwise-distance partial sums ----
// LDS layout: per tile, classes 0..31 in [64 rows][8 float4] with XOR-swizzled
// slot (q ^ ((row>>2)&7)) -> B-reads across tx cover all 8 bank groups (2-way,
// free). Class 32 in a separate [64] float array (stride-1 -> conflict-free).
__global__ __launch_bounds__(256) void pair_kernel(
    const float* __restrict__ p, const float* __restrict__ sqn,
    float* __restrict__ part_pair)
{
    __shared__ __align__(16) float4 spi[TILE * 8];
    __shared__ __align__(16) float4 spj[TILE * 8];
    __shared__ float sc32i[TILE], sc32j[TILE];
    __shared__ float ssqi[TILE], ssqj[TILE];
    __shared__ float red[4];

    int bid = blockIdx.x;
    int b = bid / NTRI;
    int t = bid % NTRI;

    // decode (ti, tj), ti <= tj, row-major upper triangle
    float disc = (NTILES + 0.5f) * (NTILES + 0.5f) - 2.0f * (float)t;
    int ti = (int)(NTILES + 0.5f - sqrtf(disc));
    if (ti < 0) ti = 0;
    if (ti > NTILES - 1) ti = NTILES - 1;
    while (ti > 0 && (ti * NTILES - ti * (ti - 1) / 2) > t) --ti;
    while (((ti + 1) * NTILES - (ti + 1) * ti / 2) <= t) ++ti;
    int tj = ti + (t - (ti * NTILES - ti * (ti - 1) / 2));

    int i0 = ti * TILE, j0 = tj * TILE;

    const float4* pb4 = (const float4*)(p + (size_t)b * NN * CP);
    for (int idx = threadIdx.x; idx < TILE * 9; idx += 256) {
        int r = idx / 9, q = idx % 9;
        float4 vi = pb4[(size_t)(i0 + r) * 9 + q];
        float4 vj = pb4[(size_t)(j0 + r) * 9 + q];
        int k = (r >> 2) & 7;
        if (q < 8) {
            spi[r * 8 + (q ^ k)] = vi;
            spj[r * 8 + (q ^ k)] = vj;
        } else {
            sc32i[r] = vi.x;
            sc32j[r] = vj.x;
        }
    }
    if (threadIdx.x < TILE)
        ssqi[threadIdx.x] = sqn[b * NN + i0 + threadIdx.x];
    else if (threadIdx.x < 2 * TILE)
        ssqj[threadIdx.x - TILE] = sqn[b * NN + j0 + (threadIdx.x - TILE)];
    __syncthreads();

    int tx = threadIdx.x & 15, ty = threadIdx.x >> 4;

    float accd[4][4];
    #pragma unroll
    for (int r = 0; r < 4; r++)
        #pragma unroll
        for (int s = 0; s < 4; s++) accd[r][s] = 0.0f;

    #pragma unroll
    for (int q = 0; q < 8; q++) {          // classes 0..31 in float4 quads
        float4 a[4], bv[4];
        #pragma unroll
        for (int r = 0; r < 4; r++) a[r] = spi[(ty * 4 + r) * 8 + (q ^ (ty & 7))];
        #pragma unroll
        for (int s = 0; s < 4; s++) bv[s] = spj[(tx * 4 + s) * 8 + (q ^ (tx & 7))];
        #pragma unroll
        for (int r = 0; r < 4; r++)
            #pragma unroll
            for (int s = 0; s < 4; s++) {
                accd[r][s] = fmaf(a[r].x, bv[s].x, accd[r][s]);
                accd[r][s] = fmaf(a[r].y, bv[s].y, accd[r][s]);
                accd[r][s] = fmaf(a[r].z, bv[s].z, accd[r][s]);
                accd[r][s] = fmaf(a[r].w, bv[s].w, accd[r][s]);
            }
    }
    {   // class 32 remainder from the conflict-free side arrays
        float a[4], bv[4];
        #pragma unroll
        for (int r = 0; r < 4; r++) a[r] = sc32i[ty * 4 + r];
        #pragma unroll
        for (int s = 0; s < 4; s++) bv[s] = sc32j[tx * 4 + s];
        #pragma unroll
        for (int r = 0; r < 4; r++)
            #pragma unroll
            for (int s = 0; s < 4; s++) accd[r][s] = fmaf(a[r], bv[s], accd[r][s]);
    }

    float ssum = 0.0f;
    #pragma unroll
    for (int r = 0; r < 4; r++) {
        int gi = i0 + ty * 4 + r;
        float sqi = ssqi[ty * 4 + r];
        #pragma unroll
        for (int s = 0; s < 4; s++) {
            int gj = j0 + tx * 4 + s;
            float d2 = sqi + ssqj[tx * 4 + s] - 2.0f * accd[r][s];
            float d = (d2 > 0.0f) ? sqrtf(d2) : 0.0f;
            ssum += (gj > gi) ? d : 0.0f;   // strict upper triangle only
        }
    }

    #pragma unroll
    for (int off = 32; off; off >>= 1) ssum += __shfl_xor(ssum, off);
    if ((threadIdx.x & 63) == 0) red[threadIdx.x >> 6] = ssum;
    __syncthreads();
    if (threadIdx.x == 0)
        part_pair[bid] = red[0] + red[1] + red[2] + red[3];
}

// ---------------- kernel 3: reduce partials + finalize -----------------------
__global__ __launch_bounds__(256) void final_kernel(
    const float2* __restrict__ part_row, const int* __restrict__ part_match,
    const float* __restrict__ part_pair, float* __restrict__ out)
{
    __shared__ double lds_ce[4], lds_fo[4], lds_pr[4];
    __shared__ int lds_mt[4];

    double ce = 0.0, fo = 0.0, pr = 0.0;
    int mt = 0;
    for (int i = threadIdx.x; i < ROWBLK; i += 256) {
        float2 v = part_row[i];
        ce += (double)v.x;
        fo += (double)v.y;
        mt += part_match[i];
    }
    for (int i = threadIdx.x; i < PAIRBLK; i += 256)
        pr += (double)part_pair[i];

    #pragma unroll
    for (int off = 32; off; off >>= 1) {
        ce += __shfl_xor(ce, off);
        fo += __shfl_xor(fo, off);
        pr += __shfl_xor(pr, off);
        mt += __shfl_xor(mt, off);
    }
    int wave = threadIdx.x >> 6;
    if ((threadIdx.x & 63) == 0) {
        lds_ce[wave] = ce; lds_fo[wave] = fo; lds_pr[wave] = pr; lds_mt[wave] = mt;
    }
    __syncthreads();
    if (threadIdx.x == 0) {
        double tce = lds_ce[0] + lds_ce[1] + lds_ce[2] + lds_ce[3];
        double tfo = lds_fo[0] + lds_fo[1] + lds_fo[2] + lds_fo[3];
        double tpr = lds_pr[0] + lds_pr[1] + lds_pr[2] + lds_pr[3];
        int    tmt = lds_mt[0] + lds_mt[1] + lds_mt[2] + lds_mt[3];

        double BN = (double)(BB * NN);
        double loss = (tce / BN) * (tfo / BN);
        double dice = 1.0 - 2.0 * ((double)tmt + 1.0) / (2.0 * BN + 1.0);
        double S = 2.0 * tpr;                    // full matrix sum (diag = 0)
        double mean_pred = S / (BN * (double)NN);
        double dml = 0.05 * log(0.05) - 0.05 * mean_pred;
        out[0] = (float)(loss + dice + dml);
    }
}

extern "C" void kernel_launch(void* const* d_in, const int* in_sizes, int n_in,
                              void* d_out, int out_size, void* d_ws, size_t ws_size,
                              hipStream_t stream)
{
    const float* pred        = (const float*)d_in[0];
    // d_in[1] = y_ohe: unused — the double-where provably collapses dis_map to 0.05
    const int*   targets     = (const int*)d_in[2];
    const int*   pred_choice = (const int*)d_in[3];

    char* ws = (char*)d_ws;
    size_t off = 0;
    float* p = (float*)ws;                                   // BB*NN*CP floats
    off += (size_t)BB * NN * CP * sizeof(float);
    float* sqn = (float*)(ws + off);
    off += (size_t)BB * NN * sizeof(float);
    off = (off + 15) & ~(size_t)15;
    float2* part_row = (float2*)(ws + off);                  // ROWBLK float2
    off += (size_t)ROWBLK * sizeof(float2);
    int* part_match = (int*)(ws + off);                      // ROWBLK int
    off += (size_t)ROWBLK * sizeof(int);
    float* part_pair = (float*)(ws + off);                   // PAIRBLK float
    off += (size_t)PAIRBLK * sizeof(float);

    row_kernel<<<ROWBLK, 256, 0, stream>>>(pred, targets, pred_choice,
                                           p, sqn, part_row, part_match);
    pair_kernel<<<PAIRBLK, 256, 0, stream>>>(p, sqn, part_pair);
    final_kernel<<<1, 256, 0, stream>>>(part_row, part_match, part_pair,
                                        (float*)d_out);
}

// Round 4
// 33.071 us; speedup vs baseline: 8.6327x; 1.4207x over previous
//
#include <hip/hip_runtime.h>
#include <math.h>

#define BB 2
#define NN 4096
#define CC 33
#define RP 40                         // bf16 row pitch in ushorts (80 B, 16B-aligned, 5x16B chunks)
#define TILE 64
#define NTILES (NN / TILE)            // 64
#define NTRI ((NTILES * (NTILES + 1)) / 2)  // 2080 upper-triangle tiles per batch
#define ROWBLK ((BB * NN) / 4)        // 2048 row-kernel blocks (4 waves = 4 rows each)
#define PAIRBLK (BB * NTRI)           // 4160 pair-kernel blocks

typedef __attribute__((ext_vector_type(8))) short frag_ab;   // 8 bf16 (4 VGPRs)
typedef __attribute__((ext_vector_type(4))) float f32x4;     // 4 fp32 accum

__device__ __forceinline__ unsigned short f2bf(float x) {
    unsigned u = __float_as_uint(x);
    return (unsigned short)((u + 0x7FFFu + ((u >> 16) & 1u)) >> 16);  // RNE, x>=0 finite
}
__device__ __forceinline__ float bf2f(unsigned short b) {
    return __uint_as_float(((unsigned)b) << 16);
}

// ---------------- kernel 1: per-row softmax -> bf16 probs + partials --------
__global__ __launch_bounds__(256) void row_kernel(
    const float* __restrict__ pred, const int* __restrict__ targets,
    const int* __restrict__ pred_choice, unsigned short* __restrict__ p16,
    float* __restrict__ sqn, float2* __restrict__ part_row,
    int* __restrict__ part_match)
{
    __shared__ float2 lds_cf[4];
    __shared__ int lds_mt[4];

    int lane = threadIdx.x & 63;
    int wave = threadIdx.x >> 6;
    int row = blockIdx.x * 4 + wave;

    float v = (lane < CC) ? pred[(size_t)row * CC + lane] : -INFINITY;

    float m = v;
    #pragma unroll
    for (int off = 32; off; off >>= 1) m = fmaxf(m, __shfl_xor(m, off));

    float e = (lane < CC) ? expf(v - m) : 0.0f;
    float s = e;
    #pragma unroll
    for (int off = 32; off; off >>= 1) s += __shfl_xor(s, off);

    float pv = e / s;                        // 0 for lanes >= 33

    unsigned short pb = f2bf(pv);            // bf16-rounded prob (0 stays 0)
    if (lane < RP) p16[(size_t)row * RP + lane] = pb;

    float pf = bf2f(pb);                     // sqn in ROUNDED space (matches MFMA dots)
    float sq = pf * pf;
    #pragma unroll
    for (int off = 32; off; off >>= 1) sq += __shfl_xor(sq, off);

    int t = targets[row];
    float vt = __shfl(v, t);
    float pt = __shfl(pv, t);
    float logpt = (vt - m) - logf(s);

    if (lane == 0) {
        sqn[row] = sq;
        float om = 1.0f - pt;
        lds_cf[wave] = make_float2(-logpt, om * om);
        lds_mt[wave] = (t == pred_choice[row]) ? 1 : 0;
    }
    __syncthreads();
    if (threadIdx.x == 0) {
        float2 a = lds_cf[0], b = lds_cf[1], c = lds_cf[2], d = lds_cf[3];
        part_row[blockIdx.x] = make_float2(a.x + b.x + c.x + d.x,
                                           a.y + b.y + c.y + d.y);
        part_match[blockIdx.x] = lds_mt[0] + lds_mt[1] + lds_mt[2] + lds_mt[3];
    }
}

// ---------------- kernel 2: 64x64 Gram tile via bf16 MFMA + distance sum ----
// LDS: [64 rows][40 ushorts] linear (80B pitch -> b128 frag reads rotate all
// 8 bank groups, conflict-free; staging copy is a linear 16B/lane memcpy).
// Classes 0..31: one mfma_f32_16x16x32_bf16 per 16x16 subtile (K=32 exact).
// Class 32: fp32 rank-1 update from ushort slot 32.
__global__ __launch_bounds__(256) void pair_kernel(
    const unsigned short* __restrict__ p16, const float* __restrict__ sqn,
    float* __restrict__ part_pair)
{
    __shared__ __align__(16) unsigned short spi[TILE * RP];
    __shared__ __align__(16) unsigned short spj[TILE * RP];
    __shared__ float ssqi[TILE], ssqj[TILE];
    __shared__ float red[4];

    int bid = blockIdx.x;
    int b = bid / NTRI;
    int t = bid % NTRI;

    // decode (ti, tj), ti <= tj, row-major upper triangle
    float disc = (NTILES + 0.5f) * (NTILES + 0.5f) - 2.0f * (float)t;
    int ti = (int)(NTILES + 0.5f - sqrtf(disc));
    if (ti < 0) ti = 0;
    if (ti > NTILES - 1) ti = NTILES - 1;
    while (ti > 0 && (ti * NTILES - ti * (ti - 1) / 2) > t) --ti;
    while (((ti + 1) * NTILES - (ti + 1) * ti / 2) <= t) ++ti;
    int tj = ti + (t - (ti * NTILES - ti * (ti - 1) / 2));

    int i0 = ti * TILE, j0 = tj * TILE;

    // linear staging: each tile is a contiguous 5120B block of p16
    const unsigned short* basei = p16 + ((size_t)b * NN + i0) * RP;
    const unsigned short* basej = p16 + ((size_t)b * NN + j0) * RP;
    for (int idx = threadIdx.x; idx < 2 * TILE * (RP / 8); idx += 256) {
        int t2 = idx >= TILE * (RP / 8);
        int k = t2 ? idx - TILE * (RP / 8) : idx;     // 0..319, byte off = k*16
        const float4* src = (const float4*)(t2 ? basej : basei) + k;
        float4* dst = (float4*)(t2 ? spj : spi) + k;
        *dst = *src;
    }
    if (threadIdx.x < TILE)
        ssqi[threadIdx.x] = sqn[b * NN + i0 + threadIdx.x];
    else if (threadIdx.x < 2 * TILE)
        ssqj[threadIdx.x - TILE] = sqn[b * NN + j0 + (threadIdx.x - TILE)];
    __syncthreads();

    int l = threadIdx.x & 63;
    int w = threadIdx.x >> 6;          // wave = 16-row strip of the i-tile
    int col = l & 15;                  // also A-row within strip
    int kc = l >> 4;                   // k-chunk 0..3 (8 bf16 each)

    // A fragment: rows 16w..16w+15 of i-tile, k = kc*8..kc*8+7
    frag_ab afr = *(const frag_ab*)&spi[(16 * w + col) * RP + kc * 8];

    // per-lane row metadata (C layout: col=lane&15, row=(lane>>4)*4+r)
    float qi[4], c32a[4];
    int gi[4];
    #pragma unroll
    for (int r = 0; r < 4; r++) {
        int ir = kc * 4 + r;           // row within strip
        qi[r]   = ssqi[16 * w + ir];
        c32a[r] = bf2f(spi[(16 * w + ir) * RP + 32]);
        gi[r]   = i0 + 16 * w + ir;
    }

    float ssum = 0.0f;
    bool diag = (ti == tj);

    #pragma unroll
    for (int n = 0; n < 4; n++) {      // 16-col subtiles of the j-tile
        frag_ab bfr = *(const frag_ab*)&spj[(16 * n + col) * RP + kc * 8];
        f32x4 acc = {0.0f, 0.0f, 0.0f, 0.0f};
        acc = __builtin_amdgcn_mfma_f32_16x16x32_bf16(afr, bfr, acc, 0, 0, 0);

        float c32b = bf2f(spj[(16 * n + col) * RP + 32]);
        float qj   = ssqj[16 * n + col];
        int   gj   = j0 + 16 * n + col;

        #pragma unroll
        for (int r = 0; r < 4; r++) {
            float g = fmaf(c32a[r], c32b, acc[r]);      // + class-32 term
            float d2 = fmaf(-2.0f, g, qi[r] + qj);
            float d = (d2 > 0.0f) ? sqrtf(d2) : 0.0f;
            if (diag) ssum += (gj > gi[r]) ? d : 0.0f;
            else      ssum += d;
        }
    }

    #pragma unroll
    for (int off = 32; off; off >>= 1) ssum += __shfl_xor(ssum, off);
    if ((threadIdx.x & 63) == 0) red[threadIdx.x >> 6] = ssum;
    __syncthreads();
    if (threadIdx.x == 0)
        part_pair[bid] = red[0] + red[1] + red[2] + red[3];
}

// ---------------- kernel 3: reduce partials + finalize -----------------------
__global__ __launch_bounds__(256) void final_kernel(
    const float2* __restrict__ part_row, const int* __restrict__ part_match,
    const float* __restrict__ part_pair, float* __restrict__ out)
{
    __shared__ double lds_ce[4], lds_fo[4], lds_pr[4];
    __shared__ int lds_mt[4];

    double ce = 0.0, fo = 0.0, pr = 0.0;
    int mt = 0;
    for (int i = threadIdx.x; i < ROWBLK; i += 256) {
        float2 v = part_row[i];
        ce += (double)v.x;
        fo += (double)v.y;
        mt += part_match[i];
    }
    for (int i = threadIdx.x; i < PAIRBLK; i += 256)
        pr += (double)part_pair[i];

    #pragma unroll
    for (int off = 32; off; off >>= 1) {
        ce += __shfl_xor(ce, off);
        fo += __shfl_xor(fo, off);
        pr += __shfl_xor(pr, off);
        mt += __shfl_xor(mt, off);
    }
    int wave = threadIdx.x >> 6;
    if ((threadIdx.x & 63) == 0) {
        lds_ce[wave] = ce; lds_fo[wave] = fo; lds_pr[wave] = pr; lds_mt[wave] = mt;
    }
    __syncthreads();
    if (threadIdx.x == 0) {
        double tce = lds_ce[0] + lds_ce[1] + lds_ce[2] + lds_ce[3];
        double tfo = lds_fo[0] + lds_fo[1] + lds_fo[2] + lds_fo[3];
        double tpr = lds_pr[0] + lds_pr[1] + lds_pr[2] + lds_pr[3];
        int    tmt = lds_mt[0] + lds_mt[1] + lds_mt[2] + lds_mt[3];

        double BN = (double)(BB * NN);
        double loss = (tce / BN) * (tfo / BN);
        double dice = 1.0 - 2.0 * ((double)tmt + 1.0) / (2.0 * BN + 1.0);
        double S = 2.0 * tpr;                    // full matrix sum (diag = 0)
        double mean_pred = S / (BN * (double)NN);
        double dml = 0.05 * log(0.05) - 0.05 * mean_pred;
        out[0] = (float)(loss + dice + dml);
    }
}

extern "C" void kernel_launch(void* const* d_in, const int* in_sizes, int n_in,
                              void* d_out, int out_size, void* d_ws, size_t ws_size,
                              hipStream_t stream)
{
    const float* pred        = (const float*)d_in[0];
    // d_in[1] = y_ohe: unused — the double-where provably collapses dis_map to 0.05
    const int*   targets     = (const int*)d_in[2];
    const int*   pred_choice = (const int*)d_in[3];

    char* ws = (char*)d_ws;
    size_t off = 0;
    unsigned short* p16 = (unsigned short*)ws;               // BB*NN*RP ushorts
    off += (size_t)BB * NN * RP * sizeof(unsigned short);
    float* sqn = (float*)(ws + off);
    off += (size_t)BB * NN * sizeof(float);
    off = (off + 15) & ~(size_t)15;
    float2* part_row = (float2*)(ws + off);                  // ROWBLK float2
    off += (size_t)ROWBLK * sizeof(float2);
    int* part_match = (int*)(ws + off);                      // ROWBLK int
    off += (size_t)ROWBLK * sizeof(int);
    float* part_pair = (float*)(ws + off);                   // PAIRBLK float
    off += (size_t)PAIRBLK * sizeof(float);

    row_kernel<<<ROWBLK, 256, 0, stream>>>(pred, targets, pred_choice,
                                           p16, sqn, part_row, part_match);
    pair_kernel<<<PAIRBLK, 256, 0, stream>>>(p16, sqn, part_pair);
    final_kernel<<<1, 256, 0, stream>>>(part_row, part_match, part_pair,
                                        (float*)d_out);
}